// Round 1
// baseline (980.230 us; speedup 1.0000x reference)
//
#include <hip/hip_runtime.h>
#include <hip/hip_bf16.h>
#include <math.h>

// Problem constants
#define BB 32
#define CI 64
#define CO 64
#define HH 128
#define WW 128
#define KK 4
#define HID 16

// ---------------------------------------------------------------------------
// Kernel 1: global average pool  g[b][c] = mean(x[b][c][:][:])
// one block per (b,c); 16384 floats each, float4 loads, wave64 reduce.
// ---------------------------------------------------------------------------
__global__ __launch_bounds__(256) void pool_kernel(const float* __restrict__ x,
                                                   float* __restrict__ g) {
    int bc = blockIdx.x;  // 0..2047
    const float4* p = reinterpret_cast<const float4*>(x + (size_t)bc * (HH * WW));
    float s = 0.f;
    for (int i = threadIdx.x; i < (HH * WW) / 4; i += 256) {
        float4 v = p[i];
        s += v.x + v.y + v.z + v.w;
    }
    // wave64 butterfly
    for (int off = 32; off > 0; off >>= 1) s += __shfl_down(s, off, 64);
    __shared__ float red[4];
    if ((threadIdx.x & 63) == 0) red[threadIdx.x >> 6] = s;
    __syncthreads();
    if (threadIdx.x == 0) {
        float tot = red[0] + red[1] + red[2] + red[3];
        g[bc] = tot * (1.0f / (HH * WW));
    }
}

// ---------------------------------------------------------------------------
// Kernel 2: attention MLP + 5 heads. One block (64 threads = 1 wave) per batch.
// ---------------------------------------------------------------------------
__global__ __launch_bounds__(64) void attn_kernel(
    const float* __restrict__ g,
    const float* __restrict__ mlp_w, const float* __restrict__ mlp_b,
    const float* __restrict__ wK, const float* __restrict__ bK,
    const float* __restrict__ wO, const float* __restrict__ bO,
    const float* __restrict__ wI, const float* __restrict__ bI,
    const float* __restrict__ wH, const float* __restrict__ bH,
    const float* __restrict__ wW, const float* __restrict__ bW,
    float* __restrict__ aK, float* __restrict__ aO, float* __restrict__ aI,
    float* __restrict__ aH, float* __restrict__ aW) {
    int b = blockIdx.x;
    int t = threadIdx.x;
    __shared__ float sg[CI];
    __shared__ float sh[HID];
    __shared__ float sK[KK];
    __shared__ float sH[3];
    __shared__ float sW[3];

    sg[t] = g[b * CI + t];
    __syncthreads();

    if (t < HID) {
        float s = mlp_b[t];
        for (int c = 0; c < CI; c++) s = fmaf(mlp_w[t * CI + c], sg[c], s);
        sh[t] = fmaxf(s, 0.f);
    }
    __syncthreads();

    // aO / aI (64 wide)
    {
        float sO = bO[t], sI = bI[t];
        for (int j = 0; j < HID; j++) {
            float hv = sh[j];
            sO = fmaf(wO[t * HID + j], hv, sO);
            sI = fmaf(wI[t * HID + j], hv, sI);
        }
        aO[b * CO + t] = 1.f / (1.f + expf(-sO));
        aI[b * CI + t] = 1.f / (1.f + expf(-sI));
    }
    if (t < KK) {
        float s = bK[t];
        for (int j = 0; j < HID; j++) s = fmaf(wK[t * HID + j], sh[j], s);
        sK[t] = s;
    }
    if (t < 3) {
        float s = bH[t];
        for (int j = 0; j < HID; j++) s = fmaf(wH[t * HID + j], sh[j], s);
        sH[t] = 1.f / (1.f + expf(-s));
        float s2 = bW[t];
        for (int j = 0; j < HID; j++) s2 = fmaf(wW[t * HID + j], sh[j], s2);
        sW[t] = 1.f / (1.f + expf(-s2));
    }
    __syncthreads();

    if (t == 0) {
        float m = fmaxf(fmaxf(sK[0], sK[1]), fmaxf(sK[2], sK[3]));
        float e0 = expf(sK[0] - m), e1 = expf(sK[1] - m);
        float e2 = expf(sK[2] - m), e3 = expf(sK[3] - m);
        float s = e0 + e1 + e2 + e3;
        aK[b * KK + 0] = e0 / s;
        aK[b * KK + 1] = e1 / s;
        aK[b * KK + 2] = e2 / s;
        aK[b * KK + 3] = e3 / s;
        float hs = sH[0] + sH[1] + sH[2] + 1e-6f;
        float wsum = sW[0] + sW[1] + sW[2] + 1e-6f;
        for (int i = 0; i < 3; i++) {
            aH[b * 3 + i] = sH[i] / hs;
            aW[b * 3 + i] = sW[i] / wsum;
        }
    }
}

// ---------------------------------------------------------------------------
// Kernel 3: dynamic weights wd[b][i][tap][o] =
//   aO[b,o]*aI[b,i]*aH[b,kh]*aW[b,kw] * sum_k aK[b,k]*weight[k,o,i,kh,kw]
// Layout [b][i][tap][o] so the conv kernel's weight staging is contiguous in o.
// ---------------------------------------------------------------------------
#define WD_TOT (BB * CI * 9 * CO)
__global__ __launch_bounds__(256) void wdyn_kernel(
    const float* __restrict__ weight,
    const float* __restrict__ aK, const float* __restrict__ aO,
    const float* __restrict__ aI, const float* __restrict__ aH,
    const float* __restrict__ aW, float* __restrict__ wd) {
    int idx = blockIdx.x * 256 + threadIdx.x;
    if (idx >= WD_TOT) return;
    int o = idx & 63;
    int r = idx >> 6;          // b*CI*9 + i*9 + tap
    int tap = r % 9;
    int bi = r / 9;            // b*CI + i
    int i = bi & 63;
    int b = bi >> 6;

    int wbase = (o * CI + i) * 9 + tap;
    const float* ak = aK + b * KK;
    float s = 0.f;
#pragma unroll
    for (int k = 0; k < KK; k++) s = fmaf(ak[k], weight[k * (CO * CI * 9) + wbase], s);
    wd[idx] = s * aO[b * CO + o] * aI[b * CI + i] *
              aH[b * 3 + tap / 3] * aW[b * 3 + tap % 3];
}

// ---------------------------------------------------------------------------
// Kernel 4: per-sample 3x3 conv, direct, fp32.
// Block: (b, oc-group of 16, 32x32 pixel tile). 256 threads.
// Thread: 4 consecutive x-pixels (px0=4*tx) x 16 oc -> 64 accumulators.
// Per 8-ic chunk: stage 8x34x36(padded) input tile + 8x9x16 weights in LDS.
// Row stride 36 floats = 144 B (16B-divisible) -> aligned float4 LDS reads.
// Weight LDS reads are wave-uniform -> broadcast, conflict-free.
// ---------------------------------------------------------------------------
#define TILE 32
#define OCB 16
#define ICB 8
__global__ __launch_bounds__(256) void conv_kernel(const float* __restrict__ x,
                                                   const float* __restrict__ wd,
                                                   const float* __restrict__ bias,
                                                   float* __restrict__ out) {
    const int b   = blockIdx.z >> 2;          // 32*4 z-blocks
    const int ocg = blockIdx.z & 3;
    const int oc0 = ocg * OCB;
    const int oy0 = blockIdx.y * TILE;
    const int ox0 = blockIdx.x * TILE;
    const int t   = threadIdx.x;
    const int tx  = t & 7;    // 8 x-groups
    const int ty  = t >> 3;   // 32 rows
    const int px0 = tx * 4;

    __shared__ __align__(16) float sx[ICB][34][36];
    __shared__ __align__(16) float sw[ICB][9][OCB];

    float acc[4][OCB];
#pragma unroll
    for (int o = 0; o < OCB; o++) {
        float bv = bias[oc0 + o];
#pragma unroll
        for (int p = 0; p < 4; p++) acc[p][o] = bv;
    }

    const float* xb  = x + (size_t)b * CI * HH * WW;
    const float* wdb = wd + (size_t)b * CI * 9 * CO;

    for (int ic0 = 0; ic0 < CI; ic0 += ICB) {
        __syncthreads();
        // stage input tile (zero-padded halo)
        for (int l = t; l < ICB * 34 * 34; l += 256) {
            int ic = l / (34 * 34);
            int rr = (l / 34) % 34;
            int cc = l % 34;
            int gy = oy0 - 1 + rr;
            int gx = ox0 - 1 + cc;
            float v = 0.f;
            if ((unsigned)gy < (unsigned)HH && (unsigned)gx < (unsigned)WW)
                v = xb[(size_t)(ic0 + ic) * (HH * WW) + gy * WW + gx];
            sx[ic][rr][cc] = v;
        }
        // stage weights
        for (int l = t; l < ICB * 9 * OCB; l += 256) {
            int ic  = l / (9 * OCB);
            int rem = l % (9 * OCB);
            int tap = rem / OCB;
            int o   = rem % OCB;
            sw[ic][tap][o] = wdb[((ic0 + ic) * 9 + tap) * CO + oc0 + o];
        }
        __syncthreads();

#pragma unroll 2
        for (int ic = 0; ic < ICB; ic++) {
#pragma unroll
            for (int kh = 0; kh < 3; kh++) {
                const float* row = &sx[ic][ty + kh][px0];
                float4 x4 = *reinterpret_cast<const float4*>(row);
                float2 x2 = *reinterpret_cast<const float2*>(row + 4);
                float xv[6] = {x4.x, x4.y, x4.z, x4.w, x2.x, x2.y};
#pragma unroll
                for (int kw = 0; kw < 3; kw++) {
                    const float* wrow = &sw[ic][kh * 3 + kw][0];
#pragma unroll
                    for (int o = 0; o < OCB; o++) {
                        float wv = wrow[o];
#pragma unroll
                        for (int p = 0; p < 4; p++)
                            acc[p][o] = fmaf(xv[p + kw], wv, acc[p][o]);
                    }
                }
            }
        }
    }

    // store 4-px vectors for each oc
#pragma unroll
    for (int o = 0; o < OCB; o++) {
        float4 v = make_float4(acc[0][o], acc[1][o], acc[2][o], acc[3][o]);
        size_t off = (((size_t)b * CO + oc0 + o) * HH + (oy0 + ty)) * WW + ox0 + px0;
        *reinterpret_cast<float4*>(&out[off]) = v;
    }
}

// ---------------------------------------------------------------------------
extern "C" void kernel_launch(void* const* d_in, const int* in_sizes, int n_in,
                              void* d_out, int out_size, void* d_ws, size_t ws_size,
                              hipStream_t stream) {
    const float* x     = (const float*)d_in[0];
    const float* weight= (const float*)d_in[1];
    const float* bias  = (const float*)d_in[2];
    const float* mlp_w = (const float*)d_in[3];
    const float* mlp_b = (const float*)d_in[4];
    const float* wK    = (const float*)d_in[5];
    const float* bK    = (const float*)d_in[6];
    const float* wO    = (const float*)d_in[7];
    const float* bO    = (const float*)d_in[8];
    const float* wI    = (const float*)d_in[9];
    const float* bI    = (const float*)d_in[10];
    const float* wH    = (const float*)d_in[11];
    const float* bH    = (const float*)d_in[12];
    const float* wW    = (const float*)d_in[13];
    const float* bW    = (const float*)d_in[14];
    float* out = (float*)d_out;

    // workspace layout (floats)
    float* ws = (float*)d_ws;
    float* g  = ws;            // 2048
    float* aK = g + 2048;      // 128
    float* aO = aK + 128;      // 2048
    float* aI = aO + 2048;     // 2048
    float* aH = aI + 2048;     // 96
    float* aW = aH + 96;       // 96
    float* wd = ws + 8192;     // 1179648

    pool_kernel<<<BB * CI, 256, 0, stream>>>(x, g);
    attn_kernel<<<BB, 64, 0, stream>>>(g, mlp_w, mlp_b, wK, bK, wO, bO, wI, bI,
                                       wH, bH, wW, bW, aK, aO, aI, aH, aW);
    wdyn_kernel<<<(WD_TOT + 255) / 256, 256, 0, stream>>>(weight, aK, aO, aI, aH, aW, wd);
    conv_kernel<<<dim3(WW / TILE, HH / TILE, BB * (CO / OCB)), 256, 0, stream>>>(x, wd, bias, out);
}

// Round 2
// 335.411 us; speedup vs baseline: 2.9225x; 2.9225x over previous
//
#include <hip/hip_runtime.h>
#include <hip/hip_bf16.h>
#include <math.h>

// Problem constants
#define BB 32
#define CI 64
#define CO 64
#define HH 128
#define WW 128
#define KK 4
#define HID 16

typedef __attribute__((ext_vector_type(8)))  __bf16 bf16x8;
typedef __attribute__((ext_vector_type(16))) float  floatx16;

__device__ __forceinline__ unsigned short f2bf(float f) {
    union { float f; unsigned int u; } a; a.f = f;
    unsigned int u = a.u;
    unsigned int r = (u + 0x7fffu + ((u >> 16) & 1u)) >> 16;  // RNE
    return (unsigned short)r;
}

// ---------------------------------------------------------------------------
// Kernel 1: global average pool  g[b][c] = mean(x[b][c][:][:])  (fp32 exact)
// ---------------------------------------------------------------------------
__global__ __launch_bounds__(256) void pool_kernel(const float* __restrict__ x,
                                                   float* __restrict__ g) {
    int bc = blockIdx.x;  // 0..2047
    const float4* p = reinterpret_cast<const float4*>(x + (size_t)bc * (HH * WW));
    float s = 0.f;
    for (int i = threadIdx.x; i < (HH * WW) / 4; i += 256) {
        float4 v = p[i];
        s += v.x + v.y + v.z + v.w;
    }
    for (int off = 32; off > 0; off >>= 1) s += __shfl_down(s, off, 64);
    __shared__ float red[4];
    if ((threadIdx.x & 63) == 0) red[threadIdx.x >> 6] = s;
    __syncthreads();
    if (threadIdx.x == 0) {
        float tot = red[0] + red[1] + red[2] + red[3];
        g[bc] = tot * (1.0f / (HH * WW));
    }
}

// ---------------------------------------------------------------------------
// Kernel 2: attention MLP + 5 heads. One wave per batch.
// ---------------------------------------------------------------------------
__global__ __launch_bounds__(64) void attn_kernel(
    const float* __restrict__ g,
    const float* __restrict__ mlp_w, const float* __restrict__ mlp_b,
    const float* __restrict__ wK, const float* __restrict__ bK,
    const float* __restrict__ wO, const float* __restrict__ bO,
    const float* __restrict__ wI, const float* __restrict__ bI,
    const float* __restrict__ wH, const float* __restrict__ bH,
    const float* __restrict__ wW, const float* __restrict__ bW,
    float* __restrict__ aK, float* __restrict__ aO, float* __restrict__ aI,
    float* __restrict__ aH, float* __restrict__ aW) {
    int b = blockIdx.x;
    int t = threadIdx.x;
    __shared__ float sg[CI];
    __shared__ float sh[HID];
    __shared__ float sK[KK];
    __shared__ float sH[3];
    __shared__ float sW[3];

    sg[t] = g[b * CI + t];
    __syncthreads();

    if (t < HID) {
        float s = mlp_b[t];
        for (int c = 0; c < CI; c++) s = fmaf(mlp_w[t * CI + c], sg[c], s);
        sh[t] = fmaxf(s, 0.f);
    }
    __syncthreads();

    {
        float sO = bO[t], sI = bI[t];
        for (int j = 0; j < HID; j++) {
            float hv = sh[j];
            sO = fmaf(wO[t * HID + j], hv, sO);
            sI = fmaf(wI[t * HID + j], hv, sI);
        }
        aO[b * CO + t] = 1.f / (1.f + expf(-sO));
        aI[b * CI + t] = 1.f / (1.f + expf(-sI));
    }
    if (t < KK) {
        float s = bK[t];
        for (int j = 0; j < HID; j++) s = fmaf(wK[t * HID + j], sh[j], s);
        sK[t] = s;
    }
    if (t < 3) {
        float s = bH[t];
        for (int j = 0; j < HID; j++) s = fmaf(wH[t * HID + j], sh[j], s);
        sH[t] = 1.f / (1.f + expf(-s));
        float s2 = bW[t];
        for (int j = 0; j < HID; j++) s2 = fmaf(wW[t * HID + j], sh[j], s2);
        sW[t] = 1.f / (1.f + expf(-s2));
    }
    __syncthreads();

    if (t == 0) {
        float m = fmaxf(fmaxf(sK[0], sK[1]), fmaxf(sK[2], sK[3]));
        float e0 = expf(sK[0] - m), e1 = expf(sK[1] - m);
        float e2 = expf(sK[2] - m), e3 = expf(sK[3] - m);
        float s = e0 + e1 + e2 + e3;
        aK[b * KK + 0] = e0 / s;
        aK[b * KK + 1] = e1 / s;
        aK[b * KK + 2] = e2 / s;
        aK[b * KK + 3] = e3 / s;
        float hs = sH[0] + sH[1] + sH[2] + 1e-6f;
        float wsum = sW[0] + sW[1] + sW[2] + 1e-6f;
        for (int i = 0; i < 3; i++) {
            aH[b * 3 + i] = sH[i] / hs;
            aW[b * 3 + i] = sW[i] / wsum;
        }
    }
}

// ---------------------------------------------------------------------------
// Kernel 3: dynamic weights -> bf16, layout wdbf[b][tap][oc][ic]
//   val = aO[b,o]*aI[b,i]*aH[b,kh]*aW[b,kw] * sum_k aK[b,k]*weight[k,o,i,kh,kw]
// ---------------------------------------------------------------------------
#define WD_TOT (BB * 9 * CO * CI)
__global__ __launch_bounds__(256) void wdyn_kernel(
    const float* __restrict__ weight,
    const float* __restrict__ aK, const float* __restrict__ aO,
    const float* __restrict__ aI, const float* __restrict__ aH,
    const float* __restrict__ aW, unsigned short* __restrict__ wdbf) {
    int idx = blockIdx.x * 256 + threadIdx.x;
    if (idx >= WD_TOT) return;
    int i   = idx & 63;
    int o   = (idx >> 6) & 63;
    int bt  = idx >> 12;     // b*9 + tap
    int tap = bt % 9;
    int b   = bt / 9;

    int wbase = (o * CI + i) * 9 + tap;
    const float* ak = aK + b * KK;
    float s = 0.f;
#pragma unroll
    for (int k = 0; k < KK; k++) s = fmaf(ak[k], weight[k * (CO * CI * 9) + wbase], s);
    float v = s * aO[b * CO + o] * aI[b * CI + i] *
              aH[b * 3 + tap / 3] * aW[b * 3 + tap % 3];
    wdbf[idx] = f2bf(v);
}

// ---------------------------------------------------------------------------
// Kernel 4: implicit-GEMM conv via v_mfma_f32_32x32x16_bf16.
// Grid: (32 row-blocks, 32 batches). Block: 512 threads = 8 waves, 4 output
// rows x 128 cols, all 64 oc. Wave: 64oc x 64px = 2x2 MFMA 32x32 tiles.
// LDS: sx[6 rows][130 cols][24 ic-slots] bf16 (16 valid ic + pad; 48B col
//      stride -> 16B-aligned, bank-uniform b128 reads), halo pre-resolved.
//      sw[9 taps][64 oc][24 ic-slots] bf16.
// K loop: 4 ic-chunks of 16 x 9 taps; per tap 4 ds_read_b128 + 4 MFMA.
// ---------------------------------------------------------------------------
#define ICCH 16
#define PADI 24
#define SX_ELE (6 * 130 * PADI)
#define SW_ELE (9 * 64 * PADI)

__global__ __launch_bounds__(512, 4) void conv_kernel(
    const float* __restrict__ x, const unsigned short* __restrict__ wdbf,
    const float* __restrict__ bias, float* __restrict__ out) {
    const int y0 = blockIdx.x * 4;
    const int b  = blockIdx.y;
    const int t  = threadIdx.x;
    const int lane = t & 63;
    const int w    = t >> 6;       // 0..7
    const int ry   = w >> 1;       // 0..3 output row within block
    const int c0   = (w & 1) * 64; // col half
    const int l31  = lane & 31;
    const int koct = lane >> 5;    // 0..1

    __shared__ __align__(16) unsigned short sx[SX_ELE];
    __shared__ __align__(16) unsigned short sw[SW_ELE];

    floatx16 acc[2][2];
#pragma unroll
    for (int i = 0; i < 2; i++)
#pragma unroll
        for (int j = 0; j < 2; j++)
#pragma unroll
            for (int q = 0; q < 16; q++) acc[i][j][q] = 0.f;

    const float* xb = x + (size_t)b * CI * HH * WW;
    const unsigned short* wdb = wdbf + (size_t)b * 9 * CO * CI;

    // per-lane fragment base offsets (ushort units)
    const int pA0 = (0 * 32 + l31) * PADI + koct * 8;
    const int pA1 = (1 * 32 + l31) * PADI + koct * 8;
    const int pB0 = (ry * 130 + c0 + 0  + l31) * PADI + koct * 8;
    const int pB1 = (ry * 130 + c0 + 32 + l31) * PADI + koct * 8;

    for (int chunk = 0; chunk < 4; chunk++) {
        const int ic0 = chunk * ICCH;
        __syncthreads();
        // ---- stage x tile (transposed, bf16, zero-padded halo) ----
        for (int idx = t; idx < 6 * 130 * 8; idx += 512) {
            int c  = idx % 130;
            int t2 = idx / 130;
            int r  = t2 % 6;
            int icp = t2 / 6;          // ic pair 0..7
            int gy = y0 - 1 + r;
            int gx = c - 1;
            float f0 = 0.f, f1 = 0.f;
            if ((unsigned)gy < (unsigned)HH && (unsigned)gx < (unsigned)WW) {
                const float* xp = xb + (size_t)(ic0 + icp * 2) * (HH * WW) + gy * WW + gx;
                f0 = xp[0];
                f1 = xp[HH * WW];
            }
            unsigned int pk = (unsigned int)f2bf(f0) | ((unsigned int)f2bf(f1) << 16);
            *reinterpret_cast<unsigned int*>(&sx[(r * 130 + c) * PADI + icp * 2]) = pk;
        }
        // ---- stage weights (b128 copies) ----
        for (int idx = t; idx < 9 * 64 * 2; idx += 512) {
            int k8  = idx & 1;
            int oc  = (idx >> 1) & 63;
            int tap = idx >> 7;
            const uint4 v = *reinterpret_cast<const uint4*>(
                wdb + ((tap * 64 + oc) * 64 + ic0 + k8 * 8));
            *reinterpret_cast<uint4*>(&sw[(tap * 64 + oc) * PADI + k8 * 8]) = v;
        }
        __syncthreads();

        // ---- MFMA over 9 taps ----
#pragma unroll
        for (int kh = 0; kh < 3; kh++) {
#pragma unroll
            for (int kw = 0; kw < 3; kw++) {
                const int tap  = kh * 3 + kw;
                const int aoff = tap * (64 * PADI);
                const int boff = (kh * 130 + kw) * PADI;
                bf16x8 a0 = *reinterpret_cast<const bf16x8*>(&sw[pA0 + aoff]);
                bf16x8 a1 = *reinterpret_cast<const bf16x8*>(&sw[pA1 + aoff]);
                bf16x8 b0 = *reinterpret_cast<const bf16x8*>(&sx[pB0 + boff]);
                bf16x8 b1 = *reinterpret_cast<const bf16x8*>(&sx[pB1 + boff]);
                acc[0][0] = __builtin_amdgcn_mfma_f32_32x32x16_bf16(a0, b0, acc[0][0], 0, 0, 0);
                acc[0][1] = __builtin_amdgcn_mfma_f32_32x32x16_bf16(a0, b1, acc[0][1], 0, 0, 0);
                acc[1][0] = __builtin_amdgcn_mfma_f32_32x32x16_bf16(a1, b0, acc[1][0], 0, 0, 0);
                acc[1][1] = __builtin_amdgcn_mfma_f32_32x32x16_bf16(a1, b1, acc[1][1], 0, 0, 0);
            }
        }
    }

    // ---- epilogue: C/D map col=lane&31, row=(reg&3)+8*(reg>>2)+4*(lane>>5) ----
    const int y = y0 + ry;
    float* ob = out + (size_t)b * CO * HH * WW + (size_t)y * WW;
#pragma unroll
    for (int mt = 0; mt < 2; mt++) {
#pragma unroll
        for (int r = 0; r < 16; r++) {
            int oc = mt * 32 + (r & 3) + 8 * (r >> 2) + 4 * koct;
            float bv = bias[oc];
            ob[(size_t)oc * (HH * WW) + c0 + l31]      = acc[mt][0][r] + bv;
            ob[(size_t)oc * (HH * WW) + c0 + l31 + 32] = acc[mt][1][r] + bv;
        }
    }
}

// ---------------------------------------------------------------------------
extern "C" void kernel_launch(void* const* d_in, const int* in_sizes, int n_in,
                              void* d_out, int out_size, void* d_ws, size_t ws_size,
                              hipStream_t stream) {
    const float* x     = (const float*)d_in[0];
    const float* weight= (const float*)d_in[1];
    const float* bias  = (const float*)d_in[2];
    const float* mlp_w = (const float*)d_in[3];
    const float* mlp_b = (const float*)d_in[4];
    const float* wK    = (const float*)d_in[5];
    const float* bK    = (const float*)d_in[6];
    const float* wO    = (const float*)d_in[7];
    const float* bO    = (const float*)d_in[8];
    const float* wI    = (const float*)d_in[9];
    const float* bI    = (const float*)d_in[10];
    const float* wH    = (const float*)d_in[11];
    const float* bH    = (const float*)d_in[12];
    const float* wW    = (const float*)d_in[13];
    const float* bW    = (const float*)d_in[14];
    float* out = (float*)d_out;

    // workspace layout
    float* ws = (float*)d_ws;
    float* g  = ws;            // 2048
    float* aK = g + 2048;      // 128
    float* aO = aK + 128;      // 2048
    float* aI = aO + 2048;     // 2048
    float* aH = aI + 2048;     // 96
    float* aW = aH + 96;       // 96
    unsigned short* wdbf = (unsigned short*)(ws + 8192);  // 32*9*64*64 bf16

    pool_kernel<<<BB * CI, 256, 0, stream>>>(x, g);
    attn_kernel<<<BB, 64, 0, stream>>>(g, mlp_w, mlp_b, wK, bK, wO, bO, wI, bI,
                                       wH, bH, wW, bW, aK, aO, aI, aH, aW);
    wdyn_kernel<<<(WD_TOT + 255) / 256, 256, 0, stream>>>(weight, aK, aO, aI, aH, aW, wdbf);
    conv_kernel<<<dim3(HH / 4, BB), 512, 0, stream>>>(x, wdbf, bias, out);
}